// Round 4
// baseline (662.618 us; speedup 1.0000x reference)
//
#include <hip/hip_runtime.h>
#include <hip/hip_bf16.h>
#include <hip/hip_fp16.h>
#include <stdint.h>

typedef __bf16 bf16x8_t __attribute__((ext_vector_type(8)));
typedef float  f32x4_t  __attribute__((ext_vector_type(4)));

#define PLANE_H   (16L * 32256 * 32)   // halves per j-group plane (33,030,144 B)
#define PSTRIDE_H 4128768L             // halves per K-split partial (8,257,536 B)

// async global->LDS, 16B per lane. LDS dest must be wave-uniform base + lane*16.
__device__ __forceinline__ void gld_lds16(const void* g, void* l) {
    __builtin_amdgcn_global_load_lds(
        (const __attribute__((address_space(1))) uint32_t*)g,
        (__attribute__((address_space(3))) uint32_t*)l, 16, 0, 0);
}

// ---------------------------------------------------------------- conv1 (fp32 vector)
__global__ __launch_bounds__(256) void k_conv1(
    const float* __restrict__ x, const float* __restrict__ w,
    const float* __restrict__ bias, __hip_bfloat16* __restrict__ y)
{
    const int b  = blockIdx.x / 92;
    const int oh = blockIdx.x % 92;
    const int oc = threadIdx.x;
    float wr[81];
#pragma unroll
    for (int t = 0; t < 81; ++t) wr[t] = w[t * 256 + oc];
    const float bs = bias[oc];
    const float* xb = x + (b * 100 + oh) * 64;
    __hip_bfloat16* yb = y + ((b * 92 + oh) * 56) * 256 + oc;
    for (int owg = 0; owg < 56; owg += 4) {
        float a0 = bs, a1 = bs, a2 = bs, a3 = bs;
#pragma unroll
        for (int kh = 0; kh < 9; ++kh) {
            const float* xr = xb + kh * 64 + owg;
            float xv[12];
#pragma unroll
            for (int t = 0; t < 12; ++t) xv[t] = xr[t];
#pragma unroll
            for (int kw = 0; kw < 9; ++kw) {
                const float wv = wr[kh * 9 + kw];
                a0 = fmaf(xv[kw + 0], wv, a0);
                a1 = fmaf(xv[kw + 1], wv, a1);
                a2 = fmaf(xv[kw + 2], wv, a2);
                a3 = fmaf(xv[kw + 3], wv, a3);
            }
        }
        yb[(owg + 0) * 256] = __float2bfloat16(fmaxf(a0, 0.f));
        yb[(owg + 1) * 256] = __float2bfloat16(fmaxf(a1, 0.f));
        yb[(owg + 2) * 256] = __float2bfloat16(fmaxf(a2, 0.f));
        yb[(owg + 3) * 256] = __float2bfloat16(fmaxf(a3, 0.f));
    }
}

// ---------------------------------------------------------------- pc_w transpose+cast
__global__ __launch_bounds__(256) void k_wt(
    const float* __restrict__ w, __hip_bfloat16* __restrict__ wt)
{
    const int idx = blockIdx.x * 256 + threadIdx.x;
    const int oc  = idx / 20736;
    const int k   = idx - oc * 20736;
    wt[idx] = __float2bfloat16(w[k * 256 + oc]);
}

// ---------------------------------------------------------------- PC conv GEMM (fallback, 128x128 2-phase)
__global__ __launch_bounds__(256, 4) void k_pcconv3(
    const __hip_bfloat16* __restrict__ y,
    const __hip_bfloat16* __restrict__ wt,
    __half* __restrict__ pbase)
{
    __shared__ __hip_bfloat16 lA[128 * 64];
    __shared__ __hip_bfloat16 lB[128 * 64];
    const int gx  = blockIdx.x;
    const int nb  = gx & 1;
    const int tm  = gx >> 1;
    const int mbx = (tm & 7) * 16 + (tm >> 3);
    if (mbx >= 126) return;
    const int z = blockIdx.y;
    __half* __restrict__ p = pbase + (long)z * PSTRIDE_H;

    const int tid  = threadIdx.x;
    const int lane = tid & 63;
    const int w    = tid >> 6;
    const int oct  = lane >> 3;
    const int c    = (lane & 7) ^ oct;

    int ybaseA[4], wbB[4];
#pragma unroll
    for (int j = 0; j < 4; ++j) {
        const int r  = w * 32 + j * 8 + oct;
        const int m  = mbx * 128 + r;
        const int b  = m / 1008;
        const int rm = m - b * 1008;
        const int oh = rm / 24;
        const int ow = rm - oh * 24;
        ybaseA[j] = ((b * 92 + 2 * oh) * 56 + 2 * ow) * 256 + c * 8;
        wbB[j]    = (nb * 128 + r) * 20736 + c * 8;
    }

    f32x4_t acc[4][4];
#pragma unroll
    for (int mi = 0; mi < 4; ++mi)
#pragma unroll
        for (int ni = 0; ni < 4; ++ni)
            acc[mi][ni] = (f32x4_t){0.f, 0.f, 0.f, 0.f};

    const int mw = (w >> 1) * 64;
    const int nw = (w & 1) * 64;
    const int lr = lane & 15;
    const int lq = lane >> 4;
    const int koff0 = ((lq + 0) ^ (lr & 7)) * 8;
    const int koff1 = ((lq + 4) ^ (lr & 7)) * 8;

    const int off = (gx * 11 + z * 5) % 27;
    for (int it = 0; it < 27; ++it) {
        const int kc   = z * 27 + ((it + off) % 27);
        const int k0   = kc * 64;
        const int khw  = k0 >> 8;
        const int ic0  = k0 & 255;
        const int kh   = khw / 9;
        const int kw2  = khw - kh * 9;
        const int aoff = (kh * 56 + kw2) * 256 + ic0;
        __syncthreads();
#pragma unroll
        for (int j = 0; j < 4; ++j)
            gld_lds16(y + ybaseA[j] + aoff, &lA[(w * 32 + j * 8) * 64 + lane * 8]);
#pragma unroll
        for (int j = 0; j < 4; ++j)
            gld_lds16(wt + wbB[j] + k0, &lB[(w * 32 + j * 8) * 64 + lane * 8]);
        __builtin_amdgcn_s_waitcnt(0);
        __syncthreads();
#pragma unroll
        for (int t = 0; t < 2; ++t) {
            const int koff = t ? koff1 : koff0;
            bf16x8_t af[4], bfr[4];
#pragma unroll
            for (int mi = 0; mi < 4; ++mi)
                af[mi] = *(const bf16x8_t*)&lA[(mw + mi * 16 + lr) * 64 + koff];
#pragma unroll
            for (int ni = 0; ni < 4; ++ni)
                bfr[ni] = *(const bf16x8_t*)&lB[(nw + ni * 16 + lr) * 64 + koff];
#pragma unroll
            for (int mi = 0; mi < 4; ++mi)
#pragma unroll
                for (int ni = 0; ni < 4; ++ni)
                    acc[mi][ni] = __builtin_amdgcn_mfma_f32_16x16x32_bf16(
                        af[mi], bfr[ni], acc[mi][ni], 0, 0, 0);
        }
    }
#pragma unroll
    for (int mi = 0; mi < 4; ++mi)
#pragma unroll
        for (int ni = 0; ni < 4; ++ni) {
            const int col = nb * 128 + nw + ni * 16 + lr;
#pragma unroll
            for (int rr = 0; rr < 4; ++rr) {
                const int row = mbx * 128 + mw + mi * 16 + lq * 4 + rr;
                p[(long)row * 256 + col] = __float2half(acc[mi][ni][rr]);
            }
        }
}

// ---------------------------------------------------------------- PC conv GEMM, 256x256, 16x16x32, 2 merged phases
// R3-verified schedule (169 us, 0 conflicts) + XCD-chunked bijective swizzle:
// physical dispatch round-robins XCDs (p%8); logical work id L is mblk-major
// (L = mblk*12 + z) so each XCD owns all 12 z-slices of ~8 consecutive mblk's.
// A-neighborhood per XCD ~5 MB (L2-fits), B LLC-shared -> cuts the 8x per-XCD
// L2-fill duplication (FETCH 373 MB vs 53 MB unique working set).
__global__ __launch_bounds__(512, 2) void k_pcconv8(
    const __hip_bfloat16* __restrict__ y,
    const __hip_bfloat16* __restrict__ wt,
    __half* __restrict__ pbase)
{
    extern __shared__ __hip_bfloat16 sm[];
    __hip_bfloat16* sA = sm;           // + buf*16384 + row*64
    __hip_bfloat16* sB = sm + 32768;   // + buf*16384 + row*64

    // bijective XCD-chunk swizzle (m204): nwg=756, q=94, r=4
    const int pphys = blockIdx.y * 63 + blockIdx.x;   // physical linear id
    const int xcd   = pphys & 7;
    const int slot  = pphys >> 3;
    const int L     = (xcd < 4 ? xcd * 95 : 380 + (xcd - 4) * 94) + slot;
    const int mblk  = L / 12;          // 0..62
    const int z     = L - mblk * 12;   // 0..11
    __half* __restrict__ p = pbase + (long)z * PSTRIDE_H;

    const int tid  = threadIdx.x;
    const int lane = tid & 63;
    const int w    = tid >> 6;         // 0..7
    const int wm   = w >> 2;           // 0..1 (M)
    const int wn   = w & 3;            // 0..3 (N)
    const int oct  = lane >> 3;
    const int c    = (lane & 7) ^ oct; // swizzled source chunk

    // staging: round i64 covers rows i64*64..+63; wave w stages rows i64*64+w*8+oct
    int ybs[4], wbs[4];
#pragma unroll
    for (int i64 = 0; i64 < 4; ++i64) {
        const int r  = i64 * 64 + w * 8 + oct;
        const int m  = mblk * 256 + r;
        const int b  = m / 1008;
        const int rm = m - b * 1008;
        const int oh = rm / 24;
        const int ow = rm - oh * 24;
        ybs[i64] = ((b * 92 + 2 * oh) * 56 + 2 * ow) * 256 + c * 8;
        wbs[i64] = r * 20736 + c * 8;
    }
    const int kbase = z * 1728;

    auto aoffk = [&](int k0) {
        const int khw = k0 >> 8;
        const int kh  = khw / 9;
        return (kh * 56 + (khw - kh * 9)) * 256 + (k0 & 255);
    };
    auto stA = [&](int i64, int buf, int aoff) {
        gld_lds16(y + ybs[i64] + aoff, sA + buf * 16384 + (i64 * 64 + w * 8) * 64 + lane * 8);
    };
    auto stB = [&](int i64, int buf, int k0) {
        gld_lds16(wt + wbs[i64] + k0, sB + buf * 16384 + (i64 * 64 + w * 8) * 64 + lane * 8);
    };

    f32x4_t acc[2][4][2][2];
#pragma unroll
    for (int mh = 0; mh < 2; ++mh)
#pragma unroll
        for (int mi = 0; mi < 4; ++mi)
#pragma unroll
            for (int nh = 0; nh < 2; ++nh)
#pragma unroll
                for (int ni = 0; ni < 2; ++ni)
                    acc[mh][mi][nh][ni] = (f32x4_t){0.f, 0.f, 0.f, 0.f};

    const int lr = lane & 15;
    const int lq = lane >> 4;
    const int koff0 = ((lq + 0) ^ (lr & 7)) * 8;
    const int koff1 = ((lq + 4) ^ (lr & 7)) * 8;

    bf16x8_t af[4][2], bf0[2][2], bf1[2][2];

#define RD_A(CUR, MH)                                                                   \
    _Pragma("unroll") for (int mi = 0; mi < 4; ++mi) {                                  \
        const __hip_bfloat16* ap =                                                      \
            sA + (CUR) * 16384 + (wm * 128 + (MH) * 64 + mi * 16 + lr) * 64;            \
        af[mi][0] = *(const bf16x8_t*)(ap + koff0);                                     \
        af[mi][1] = *(const bf16x8_t*)(ap + koff1);                                     \
    }
#define RD_B(DST, CUR, NH)                                                              \
    _Pragma("unroll") for (int ni = 0; ni < 2; ++ni) {                                  \
        const __hip_bfloat16* bp =                                                      \
            sB + (CUR) * 16384 + (wn * 64 + (NH) * 32 + ni * 16 + lr) * 64;             \
        DST[ni][0] = *(const bf16x8_t*)(bp + koff0);                                    \
        DST[ni][1] = *(const bf16x8_t*)(bp + koff1);                                    \
    }
#define MFMA_Q(MH, NH, BF)                                                              \
    _Pragma("unroll") for (int mi = 0; mi < 4; ++mi)                                    \
    _Pragma("unroll") for (int ni = 0; ni < 2; ++ni) {                                  \
        acc[MH][mi][NH][ni] = __builtin_amdgcn_mfma_f32_16x16x32_bf16(                  \
            af[mi][0], BF[ni][0], acc[MH][mi][NH][ni], 0, 0, 0);                        \
        acc[MH][mi][NH][ni] = __builtin_amdgcn_mfma_f32_16x16x32_bf16(                  \
            af[mi][1], BF[ni][1], acc[MH][mi][NH][ni], 0, 0, 0);                        \
    }

    // prologue: stage tile 0 into buf 0 (oldest-first order matches steady state)
    {
        const int k0 = kbase;
        const int ao = aoffk(k0);
        stB(0, 0, k0); stB(1, 0, k0); stB(2, 0, k0); stB(3, 0, k0);
        stA(0, 0, ao); stA(2, 0, ao); stA(1, 0, ao); stA(3, 0, ao);
    }
    asm volatile("s_waitcnt vmcnt(2)" ::: "memory");   // B0-3, A0, A2 landed
    __builtin_amdgcn_s_barrier();

    for (int kt = 0; kt < 26; ++kt) {
        const int cur = kt & 1, nxt = cur ^ 1;
        const int k0n = kbase + (kt + 1) * 64;
        const int aon = aoffk(k0n);
        // ---- P0: compute MH0 x {NT0,NT1}; stage B0-3 of t+1
        RD_A(cur, 0);
        RD_B(bf0, cur, 0);
        RD_B(bf1, cur, 1);
        stB(0, nxt, k0n); stB(1, nxt, k0n); stB(2, nxt, k0n); stB(3, nxt, k0n);
        __builtin_amdgcn_s_barrier();
        asm volatile("s_waitcnt lgkmcnt(0)" ::: "memory");
        __builtin_amdgcn_s_setprio(1);
        MFMA_Q(0, 0, bf0);
        MFMA_Q(0, 1, bf1);
        __builtin_amdgcn_s_setprio(0);
        asm volatile("s_waitcnt vmcnt(4)" ::: "memory");   // A1,A3 of t landed
        __builtin_amdgcn_s_barrier();
        // ---- P1: compute MH1 x {NT1,NT0}; stage A0,A2,A1,A3 of t+1
        RD_A(cur, 1);
        stA(0, nxt, aon); stA(2, nxt, aon); stA(1, nxt, aon); stA(3, nxt, aon);
        __builtin_amdgcn_s_barrier();
        asm volatile("s_waitcnt lgkmcnt(0)" ::: "memory");
        __builtin_amdgcn_s_setprio(1);
        MFMA_Q(1, 1, bf1);
        MFMA_Q(1, 0, bf0);
        __builtin_amdgcn_s_setprio(0);
        asm volatile("s_waitcnt vmcnt(2)" ::: "memory");   // B0-3,A0,A2 of t+1 landed
        __builtin_amdgcn_s_barrier();
    }

    // epilogue tile 26 (cur = 0, no staging); entry in-flight = 2 [A1,A3]
    RD_A(0, 0);
    RD_B(bf0, 0, 0);
    RD_B(bf1, 0, 1);
    __builtin_amdgcn_s_barrier();
    asm volatile("s_waitcnt lgkmcnt(0)" ::: "memory");
    __builtin_amdgcn_s_setprio(1);
    MFMA_Q(0, 0, bf0);
    MFMA_Q(0, 1, bf1);
    __builtin_amdgcn_s_setprio(0);
    asm volatile("s_waitcnt vmcnt(0)" ::: "memory");   // A1,A3 of tile 26
    __builtin_amdgcn_s_barrier();
    RD_A(0, 1);
    asm volatile("s_waitcnt lgkmcnt(0)" ::: "memory");
    __builtin_amdgcn_s_setprio(1);
    MFMA_Q(1, 1, bf1);
    MFMA_Q(1, 0, bf0);
    __builtin_amdgcn_s_setprio(0);

#undef RD_A
#undef RD_B
#undef MFMA_Q

    // C-write: frag layout col=lane&15, row=(lane>>4)*4+rr
#pragma unroll
    for (int mh = 0; mh < 2; ++mh)
#pragma unroll
        for (int mi = 0; mi < 4; ++mi)
#pragma unroll
            for (int nh = 0; nh < 2; ++nh)
#pragma unroll
                for (int ni = 0; ni < 2; ++ni) {
                    const int col = wn * 64 + nh * 32 + ni * 16 + lr;
#pragma unroll
                    for (int rr = 0; rr < 4; ++rr) {
                        const int row = mblk * 256 + wm * 128 + mh * 64 + mi * 16 + lq * 4 + rr;
                        p[(long)row * 256 + col] = __float2half(acc[mh][mi][nh][ni][rr]);
                    }
                }
}

// ---------------------------------------------------------------- squash (sums 12 fp16 K-splits)
__global__ __launch_bounds__(256) void k_squash(
    const __half* __restrict__ Ph, const float* __restrict__ bias, float* __restrict__ u)
{
    const int g = blockIdx.x * 256 + threadIdx.x;   // < 516096
    const long base = (long)g * 8;
    const int cb = (g & 31) * 8;
    float v[8];
#pragma unroll
    for (int t = 0; t < 8; ++t) v[t] = bias[cb + t];
#pragma unroll
    for (int z = 0; z < 12; ++z) {
        const uint4 r = *(const uint4*)(Ph + z * PSTRIDE_H + base);
        const unsigned wd[4] = {r.x, r.y, r.z, r.w};
#pragma unroll
        for (int h2 = 0; h2 < 4; ++h2) {
            const __half2 hh = *(const __half2*)&wd[h2];
            v[h2 * 2 + 0] += __low2float(hh);
            v[h2 * 2 + 1] += __high2float(hh);
        }
    }
    float sq = 0.f;
#pragma unroll
    for (int t = 0; t < 8; ++t) sq += v[t] * v[t];
    const float sc = sq / ((1.f + sq) * sqrtf(sq + 1e-7f));
#pragma unroll
    for (int t = 0; t < 8; ++t) u[base + t] = v[t] * sc;
}

// ---------------------------------------------------------------- u_hat precompute + fused iter-0 s
// W tile (64 VGPR) loaded ONCE per jg and reused for BOTH b-halves -> W HBM/L2
// traffic halved vs the old grid(2,504) layout (two blocks loading same W).
__global__ __launch_bounds__(256) void k_uhat2(
    const float* __restrict__ u, const float* __restrict__ W, __half* __restrict__ uh,
    float* __restrict__ sp0)
{
    __shared__ __half lbuf[8 * 64 * 32];   // 32 KB
    __shared__ float red[4 * 256];         // 4 KB
    const int ic   = blockIdx.x;           // 0..503
    const int tid  = threadIdx.x;
    const int lane = tid & 63;
    const int wv   = tid >> 6;
    const int q    = tid & 3;              // d-quarter
    const int il   = tid >> 2;             // 0..64
    const int i    = ic * 64 + il;

    for (int jg = 0; jg < 5; ++jg) {
        const float* wb0 = W + ((long)(2 * jg) * 32256 + i) * 128 + q * 32;
        const float* wb1 = wb0 + (long)32256 * 128;
        float4 w0[8], w1[8];
#pragma unroll
        for (int t = 0; t < 8; ++t) w0[t] = *(const float4*)(wb0 + t * 4);
#pragma unroll
        for (int t = 0; t < 8; ++t) w1[t] = *(const float4*)(wb1 + t * 4);
        for (int bh = 0; bh < 2; ++bh) {
            if (jg | bh) __syncthreads();  // previous flush/reduce must finish
#pragma unroll
            for (int b = 0; b < 8; ++b) {
                const float* up = u + ((bh * 8 + b) * 32256 + i) * 8;
                const float4 u0 = *(const float4*)up;
                const float4 u1 = *(const float4*)(up + 4);
                union { __half h[8]; uint4 v; } pk;
#pragma unroll
                for (int d = 0; d < 4; ++d) {
                    const float4 a = w0[2 * d], cc = w0[2 * d + 1];
                    pk.h[d] = __float2half(
                        a.x * u0.x + a.y * u0.y + a.z * u0.z + a.w * u0.w +
                        cc.x * u1.x + cc.y * u1.y + cc.z * u1.z + cc.w * u1.w);
                }
#pragma unroll
                for (int d = 0; d < 4; ++d) {
                    const float4 a = w1[2 * d], cc = w1[2 * d + 1];
                    pk.h[4 + d] = __float2half(
                        a.x * u0.x + a.y * u0.y + a.z * u0.z + a.w * u0.w +
                        cc.x * u1.x + cc.y * u1.y + cc.z * u1.z + cc.w * u1.w);
                }
                *(uint4*)&lbuf[(b * 64 + il) * 32 + q * 8] = pk.v;
                float rv[8];
#pragma unroll
                for (int t = 0; t < 8; ++t) rv[t] = __half2float(pk.h[t]);
#pragma unroll
                for (int t = 0; t < 8; ++t) {
                    rv[t] += __shfl_xor(rv[t], 4);
                    rv[t] += __shfl_xor(rv[t], 8);
                    rv[t] += __shfl_xor(rv[t], 16);
                    rv[t] += __shfl_xor(rv[t], 32);
                }
                if (lane < 4) {
#pragma unroll
                    for (int t = 0; t < 8; ++t)
                        red[wv * 256 + b * 32 + (t >> 2) * 16 + q * 4 + (t & 3)] = rv[t];
                }
            }
            __syncthreads();
            __half* pb = uh + (long)jg * PLANE_H + ((long)(bh * 8) * 32256 + ic * 64) * 32;
#pragma unroll
            for (int b = 0; b < 8; ++b) {
                const uint4 v = *(const uint4*)&lbuf[b * 2048 + tid * 8];
                *(uint4*)(pb + (long)b * (32256 * 32) + tid * 8) = v;
            }
            {
                const float v = red[tid] + red[256 + tid] + red[512 + tid] + red[768 + tid];
                const int bb = tid >> 5, j2 = (tid >> 4) & 1, dd = tid & 15;
                atomicAdd(&sp0[((bh * 8 + bb) * 10 + (2 * jg + j2)) * 16 + dd], 0.1f * v);
            }
        }
    }
}

// ---------------------------------------------------------------- routing iteration
// ps-loop double-buffered: issue ps+1's 5 independent 16B loads before the
// dependent unpack/softmax VALU chain of ps -> hides L2/HBM latency.
__global__ __launch_bounds__(256) void k_route4(
    const __half* __restrict__ uh, const float* __restrict__ vsum,
    float* __restrict__ sp)
{
    __shared__ float red[4 * 160];
    const int b     = blockIdx.x;      // 16
    const int chunk = blockIdx.y;      // 56
    const int tid   = threadIdx.x;
    const int lane  = tid & 63;
    const int wv    = tid >> 6;
    const int q     = lane & 3;
    const int ig    = lane >> 2;

    float vs[10][4];
#pragma unroll
    for (int j = 0; j < 10; ++j) {
        const float4 t = *(const float4*)(vsum + (b * 10 + j) * 16 + q * 4);
        vs[j][0] = t.x; vs[j][1] = t.y; vs[j][2] = t.z; vs[j][3] = t.w;
    }
    float acc[10][4];
#pragma unroll
    for (int j = 0; j < 10; ++j)
#pragma unroll
        for (int t = 0; t < 4; ++t) acc[j][t] = 0.f;

    const int ib = chunk * 576 + wv * 16 + ig;
    const long rbase = ((long)b * 32256 + ib) * 32 + q * 8;
    uint4 r[5];
#pragma unroll
    for (int jg = 0; jg < 5; ++jg)
        r[jg] = *(const uint4*)(uh + jg * PLANE_H + rbase);
    for (int ps = 0; ps < 9; ++ps) {
        uint4 rn[5];
        if (ps < 8) {
            const long rb2 = rbase + (long)(ps + 1) * 2048;
#pragma unroll
            for (int jg = 0; jg < 5; ++jg)
                rn[jg] = *(const uint4*)(uh + jg * PLANE_H + rb2);
        }
        float uhf[10][4];
#pragma unroll
        for (int jg = 0; jg < 5; ++jg) {
            const unsigned wd[4] = {r[jg].x, r[jg].y, r[jg].z, r[jg].w};
#pragma unroll
            for (int h2 = 0; h2 < 4; ++h2) {
                const __half2 hh = *(const __half2*)&wd[h2];
                const int j  = jg * 2 + (h2 >> 1);
                const int d0 = (h2 & 1) * 2;
                uhf[j][d0 + 0] = __low2float(hh);
                uhf[j][d0 + 1] = __high2float(hh);
            }
        }
        float logit[10];
#pragma unroll
        for (int j = 0; j < 10; ++j) {
            float lg = vs[j][0] * uhf[j][0] + vs[j][1] * uhf[j][1]
                     + vs[j][2] * uhf[j][2] + vs[j][3] * uhf[j][3];
            lg += __shfl_xor(lg, 1);
            lg += __shfl_xor(lg, 2);
            logit[j] = lg;
        }
        float mx = logit[0];
#pragma unroll
        for (int j = 1; j < 10; ++j) mx = fmaxf(mx, logit[j]);
        float den = 0.f, e[10];
#pragma unroll
        for (int j = 0; j < 10; ++j) { e[j] = __expf(logit[j] - mx); den += e[j]; }
        const float inv = __builtin_amdgcn_rcpf(den);
#pragma unroll
        for (int j = 0; j < 10; ++j) {
            const float c = e[j] * inv;
#pragma unroll
            for (int t = 0; t < 4; ++t) acc[j][t] = fmaf(c, uhf[j][t], acc[j][t]);
        }
        if (ps < 8) {
#pragma unroll
            for (int jg = 0; jg < 5; ++jg) r[jg] = rn[jg];
        }
    }
#pragma unroll
    for (int j = 0; j < 10; ++j)
#pragma unroll
        for (int t = 0; t < 4; ++t) {
            float v2 = acc[j][t];
            v2 += __shfl_xor(v2, 4);
            v2 += __shfl_xor(v2, 8);
            v2 += __shfl_xor(v2, 16);
            v2 += __shfl_xor(v2, 32);
            if (lane < 4) red[wv * 160 + j * 16 + q * 4 + t] = v2;
        }
    __syncthreads();
    if (tid < 160) {
        const float s = red[tid] + red[160 + tid] + red[320 + tid] + red[480 + tid];
        atomicAdd(&sp[b * 160 + tid], s);
    }
}

// ---------------------------------------------------------------- v = squash(s); vsum += v
__global__ void k_finish(const float* __restrict__ sp, float* __restrict__ vsum,
                         float* __restrict__ out, const int fin)
{
    const int t = threadIdx.x;
    if (t >= 160) return;          // t = b*10 + j
    const float* s = sp + t * 16;
    float sv[16]; float sq = 0.f;
#pragma unroll
    for (int d = 0; d < 16; ++d) { sv[d] = s[d]; sq += sv[d] * sv[d]; }
    const float sc = sq / ((1.f + sq) * sqrtf(sq + 1e-7f));
    if (fin) {
#pragma unroll
        for (int d = 0; d < 16; ++d) out[t * 16 + d] = sv[d] * sc;
    } else {
        float* vp = vsum + t * 16;
#pragma unroll
        for (int d = 0; d < 16; ++d) vp[d] += sv[d] * sc;
    }
}

extern "C" void kernel_launch(void* const* d_in, const int* in_sizes, int n_in,
                              void* d_out, int out_size, void* d_ws, size_t ws_size,
                              hipStream_t stream)
{
    const float* x   = (const float*)d_in[0];
    const float* c1w = (const float*)d_in[1];
    const float* c1b = (const float*)d_in[2];
    const float* pcw = (const float*)d_in[3];
    const float* pcb = (const float*)d_in[4];
    const float* cW  = (const float*)d_in[5];
    float* out = (float*)d_out;

    char* ws = (char*)d_ws;
    float* u  = (float*)(ws);                                   // 16,515,072 B
    __half* Ph = (__half*)(ws + 16515072);                      // 99,090,432 B
    __hip_bfloat16* y  = (__hip_bfloat16*)(ws + 115605504);     // 42,205,184 B
    __hip_bfloat16* wt = (__hip_bfloat16*)(ws + 157810688);     // 10,616,832 B
    __half* uh = (__half*)(ws + 16515072);                      // 165,150,720 B
    float* sp   = (float*)(ws + 181665792);                     // 3*2560*4 B
    float* vsum = (float*)(ws + 181696512);                     // 2560*4 B

    static int pc8_ok = -1;
    if (pc8_ok < 0)
        pc8_ok = (hipFuncSetAttribute((const void*)k_pcconv8,
                    hipFuncAttributeMaxDynamicSharedMemorySize, 131072) == hipSuccess)
                 ? 1 : 0;

    hipMemsetAsync(sp, 0, (3 * 2560 + 2560) * 4, stream);

    k_conv1<<<16 * 92, 256, 0, stream>>>(x, c1w, c1b, y);
    k_wt<<<20736, 256, 0, stream>>>(pcw, wt);
    if (pc8_ok)
        k_pcconv8<<<dim3(63, 12), 512, 131072, stream>>>(y, wt, Ph);
    else
        k_pcconv3<<<dim3(256, 12), 256, 0, stream>>>(y, wt, Ph);
    k_squash<<<2016, 256, 0, stream>>>(Ph, pcb, u);
    k_uhat2<<<504, 256, 0, stream>>>(u, cW, uh, sp);              // fused iter-0 s
    k_finish<<<1, 256, 0, stream>>>(sp, vsum, out, 0);            // v0 -> vsum
    k_route4<<<dim3(16, 56), 256, 0, stream>>>(uh, vsum, sp + 2560);
    k_finish<<<1, 256, 0, stream>>>(sp + 2560, vsum, out, 0);     // v1 -> vsum
    k_route4<<<dim3(16, 56), 256, 0, stream>>>(uh, vsum, sp + 5120);
    k_finish<<<1, 256, 0, stream>>>(sp + 5120, vsum, out, 1);     // v2 -> out
}

// Round 5
// 635.480 us; speedup vs baseline: 1.0427x; 1.0427x over previous
//
#include <hip/hip_runtime.h>
#include <hip/hip_bf16.h>
#include <hip/hip_fp16.h>
#include <stdint.h>

typedef __bf16 bf16x8_t __attribute__((ext_vector_type(8)));
typedef float  f32x4_t  __attribute__((ext_vector_type(4)));

#define PLANE_H   (16L * 32256 * 32)   // halves per j-group plane (33,030,144 B)
#define PSTRIDE_H 4128768L             // halves per K-split partial (8,257,536 B)

// async global->LDS, 16B per lane. LDS dest must be wave-uniform base + lane*16.
__device__ __forceinline__ void gld_lds16(const void* g, void* l) {
    __builtin_amdgcn_global_load_lds(
        (const __attribute__((address_space(1))) uint32_t*)g,
        (__attribute__((address_space(3))) uint32_t*)l, 16, 0, 0);
}

// fused "wait N outstanding VMEM, then barrier" — single asm so nothing can be
// scheduled between the wait and the barrier; memory clobber stops the compiler
// from moving LDS/global ops across the sync point (raw s_barrier builtin is
// NOT a compiler fence).
#define VMCNT_BAR(N) asm volatile("s_waitcnt vmcnt(" #N ")\n\ts_barrier" ::: "memory")

// ---------------------------------------------------------------- conv1 (fp32 vector)
__global__ __launch_bounds__(256) void k_conv1(
    const float* __restrict__ x, const float* __restrict__ w,
    const float* __restrict__ bias, __hip_bfloat16* __restrict__ y)
{
    const int b  = blockIdx.x / 92;
    const int oh = blockIdx.x % 92;
    const int oc = threadIdx.x;
    float wr[81];
#pragma unroll
    for (int t = 0; t < 81; ++t) wr[t] = w[t * 256 + oc];
    const float bs = bias[oc];
    const float* xb = x + (b * 100 + oh) * 64;
    __hip_bfloat16* yb = y + ((b * 92 + oh) * 56) * 256 + oc;
    for (int owg = 0; owg < 56; owg += 4) {
        float a0 = bs, a1 = bs, a2 = bs, a3 = bs;
#pragma unroll
        for (int kh = 0; kh < 9; ++kh) {
            const float* xr = xb + kh * 64 + owg;
            float xv[12];
#pragma unroll
            for (int t = 0; t < 12; ++t) xv[t] = xr[t];
#pragma unroll
            for (int kw = 0; kw < 9; ++kw) {
                const float wv = wr[kh * 9 + kw];
                a0 = fmaf(xv[kw + 0], wv, a0);
                a1 = fmaf(xv[kw + 1], wv, a1);
                a2 = fmaf(xv[kw + 2], wv, a2);
                a3 = fmaf(xv[kw + 3], wv, a3);
            }
        }
        yb[(owg + 0) * 256] = __float2bfloat16(fmaxf(a0, 0.f));
        yb[(owg + 1) * 256] = __float2bfloat16(fmaxf(a1, 0.f));
        yb[(owg + 2) * 256] = __float2bfloat16(fmaxf(a2, 0.f));
        yb[(owg + 3) * 256] = __float2bfloat16(fmaxf(a3, 0.f));
    }
}

// ---------------------------------------------------------------- pc_w transpose+cast
__global__ __launch_bounds__(256) void k_wt(
    const float* __restrict__ w, __hip_bfloat16* __restrict__ wt)
{
    const int idx = blockIdx.x * 256 + threadIdx.x;
    const int oc  = idx / 20736;
    const int k   = idx - oc * 20736;
    wt[idx] = __float2bfloat16(w[k * 256 + oc]);
}

// ---------------------------------------------------------------- PC conv GEMM (fallback, 128x128 2-phase)
__global__ __launch_bounds__(256, 4) void k_pcconv3(
    const __hip_bfloat16* __restrict__ y,
    const __hip_bfloat16* __restrict__ wt,
    __half* __restrict__ pbase)
{
    __shared__ __hip_bfloat16 lA[128 * 64];
    __shared__ __hip_bfloat16 lB[128 * 64];
    const int gx  = blockIdx.x;
    const int nb  = gx & 1;
    const int tm  = gx >> 1;
    const int mbx = (tm & 7) * 16 + (tm >> 3);
    if (mbx >= 126) return;
    const int z = blockIdx.y;
    __half* __restrict__ p = pbase + (long)z * PSTRIDE_H;

    const int tid  = threadIdx.x;
    const int lane = tid & 63;
    const int w    = tid >> 6;
    const int oct  = lane >> 3;
    const int c    = (lane & 7) ^ oct;

    int ybaseA[4], wbB[4];
#pragma unroll
    for (int j = 0; j < 4; ++j) {
        const int r  = w * 32 + j * 8 + oct;
        const int m  = mbx * 128 + r;
        const int b  = m / 1008;
        const int rm = m - b * 1008;
        const int oh = rm / 24;
        const int ow = rm - oh * 24;
        ybaseA[j] = ((b * 92 + 2 * oh) * 56 + 2 * ow) * 256 + c * 8;
        wbB[j]    = (nb * 128 + r) * 20736 + c * 8;
    }

    f32x4_t acc[4][4];
#pragma unroll
    for (int mi = 0; mi < 4; ++mi)
#pragma unroll
        for (int ni = 0; ni < 4; ++ni)
            acc[mi][ni] = (f32x4_t){0.f, 0.f, 0.f, 0.f};

    const int mw = (w >> 1) * 64;
    const int nw = (w & 1) * 64;
    const int lr = lane & 15;
    const int lq = lane >> 4;
    const int koff0 = ((lq + 0) ^ (lr & 7)) * 8;
    const int koff1 = ((lq + 4) ^ (lr & 7)) * 8;

    const int off = (gx * 11 + z * 5) % 27;
    for (int it = 0; it < 27; ++it) {
        const int kc   = z * 27 + ((it + off) % 27);
        const int k0   = kc * 64;
        const int khw  = k0 >> 8;
        const int ic0  = k0 & 255;
        const int kh   = khw / 9;
        const int kw2  = khw - kh * 9;
        const int aoff = (kh * 56 + kw2) * 256 + ic0;
        __syncthreads();
#pragma unroll
        for (int j = 0; j < 4; ++j)
            gld_lds16(y + ybaseA[j] + aoff, &lA[(w * 32 + j * 8) * 64 + lane * 8]);
#pragma unroll
        for (int j = 0; j < 4; ++j)
            gld_lds16(wt + wbB[j] + k0, &lB[(w * 32 + j * 8) * 64 + lane * 8]);
        __builtin_amdgcn_s_waitcnt(0);
        __syncthreads();
#pragma unroll
        for (int t = 0; t < 2; ++t) {
            const int koff = t ? koff1 : koff0;
            bf16x8_t af[4], bfr[4];
#pragma unroll
            for (int mi = 0; mi < 4; ++mi)
                af[mi] = *(const bf16x8_t*)&lA[(mw + mi * 16 + lr) * 64 + koff];
#pragma unroll
            for (int ni = 0; ni < 4; ++ni)
                bfr[ni] = *(const bf16x8_t*)&lB[(nw + ni * 16 + lr) * 64 + koff];
#pragma unroll
            for (int mi = 0; mi < 4; ++mi)
#pragma unroll
                for (int ni = 0; ni < 4; ++ni)
                    acc[mi][ni] = __builtin_amdgcn_mfma_f32_16x16x32_bf16(
                        af[mi], bfr[ni], acc[mi][ni], 0, 0, 0);
        }
    }
#pragma unroll
    for (int mi = 0; mi < 4; ++mi)
#pragma unroll
        for (int ni = 0; ni < 4; ++ni) {
            const int col = nb * 128 + nw + ni * 16 + lr;
#pragma unroll
            for (int rr = 0; rr < 4; ++rr) {
                const int row = mbx * 128 + mw + mi * 16 + lq * 4 + rr;
                p[(long)row * 256 + col] = __float2half(acc[mi][ni][rr]);
            }
        }
}

// ---------------------------------------------------------------- PC conv GEMM, 256x256, relaxed-drain 2-phase
// R4 diag: FETCH halved (XCD swizzle) but dur flat -> NOT memory-bound. The
// binding constraint was the forced full lgkmcnt(0) drain + barrier between
// the 24 ds_read_b128 and the MFMA cluster: CU-wide LDS drain (~2050 cyc/tile)
// serialized against MFMA (~620 cyc/SIMD) => 44% MfmaUtil.
// THIS VERSION: only TWO sync points per K-tile (vmcnt(4)+bar, vmcnt(2)+bar).
// No mid-phase barrier, no lgkmcnt(0): the compiler's fine-grained lgkm waits
// let MFMA start as soon as its first fragments land, overlapping the drain.
// Safety: data read in a phase was published by the PREVIOUS tile's
// vmcnt+barrier; all reads of the buffer being overwritten are register-
// complete before the preceding barrier (each ds_read is lgkm-waited before
// its consuming MFMA, which precedes that barrier in program order).
// In-flight ledger: entry 2 [A1,A3(t)] -> P0 +4 stB -> 6 -> vmcnt(4) retires
// A1,A3(t) -> P1 +4 stA -> 8 -> vmcnt(2) retires B0-3,A0,A2(t+1) -> 2. steady.
__global__ __launch_bounds__(512, 2) void k_pcconv8(
    const __hip_bfloat16* __restrict__ y,
    const __hip_bfloat16* __restrict__ wt,
    __half* __restrict__ pbase)
{
    extern __shared__ __hip_bfloat16 sm[];
    __hip_bfloat16* sA = sm;           // + buf*16384 + row*64
    __hip_bfloat16* sB = sm + 32768;   // + buf*16384 + row*64

    // bijective XCD-chunk swizzle (m204): nwg=756, q=94, r=4
    const int pphys = blockIdx.y * 63 + blockIdx.x;   // physical linear id
    const int xcd   = pphys & 7;
    const int slot  = pphys >> 3;
    const int L     = (xcd < 4 ? xcd * 95 : 380 + (xcd - 4) * 94) + slot;
    const int mblk  = L / 12;          // 0..62
    const int z     = L - mblk * 12;   // 0..11
    __half* __restrict__ p = pbase + (long)z * PSTRIDE_H;

    const int tid  = threadIdx.x;
    const int lane = tid & 63;
    const int w    = tid >> 6;         // 0..7
    const int wm   = w >> 2;           // 0..1 (M)
    const int wn   = w & 3;            // 0..3 (N)
    const int oct  = lane >> 3;
    const int c    = (lane & 7) ^ oct; // swizzled source chunk

    // staging: round i64 covers rows i64*64..+63; wave w stages rows i64*64+w*8+oct
    int ybs[4], wbs[4];
#pragma unroll
    for (int i64 = 0; i64 < 4; ++i64) {
        const int r  = i64 * 64 + w * 8 + oct;
        const int m  = mblk * 256 + r;
        const int b  = m / 1008;
        const int rm = m - b * 1008;
        const int oh = rm / 24;
        const int ow = rm - oh * 24;
        ybs[i64] = ((b * 92 + 2 * oh) * 56 + 2 * ow) * 256 + c * 8;
        wbs[i64] = r * 20736 + c * 8;
    }
    const int kbase = z * 1728;

    auto aoffk = [&](int k0) {
        const int khw = k0 >> 8;
        const int kh  = khw / 9;
        return (kh * 56 + (khw - kh * 9)) * 256 + (k0 & 255);
    };
    auto stA = [&](int i64, int buf, int aoff) {
        gld_lds16(y + ybs[i64] + aoff, sA + buf * 16384 + (i64 * 64 + w * 8) * 64 + lane * 8);
    };
    auto stB = [&](int i64, int buf, int k0) {
        gld_lds16(wt + wbs[i64] + k0, sB + buf * 16384 + (i64 * 64 + w * 8) * 64 + lane * 8);
    };

    f32x4_t acc[2][4][2][2];
#pragma unroll
    for (int mh = 0; mh < 2; ++mh)
#pragma unroll
        for (int mi = 0; mi < 4; ++mi)
#pragma unroll
            for (int nh = 0; nh < 2; ++nh)
#pragma unroll
                for (int ni = 0; ni < 2; ++ni)
                    acc[mh][mi][nh][ni] = (f32x4_t){0.f, 0.f, 0.f, 0.f};

    const int lr = lane & 15;
    const int lq = lane >> 4;
    const int koff0 = ((lq + 0) ^ (lr & 7)) * 8;
    const int koff1 = ((lq + 4) ^ (lr & 7)) * 8;

    bf16x8_t af[4][2], bf0[2][2], bf1[2][2];

#define RD_A(CUR, MH)                                                                   \
    _Pragma("unroll") for (int mi = 0; mi < 4; ++mi) {                                  \
        const __hip_bfloat16* ap =                                                      \
            sA + (CUR) * 16384 + (wm * 128 + (MH) * 64 + mi * 16 + lr) * 64;            \
        af[mi][0] = *(const bf16x8_t*)(ap + koff0);                                     \
        af[mi][1] = *(const bf16x8_t*)(ap + koff1);                                     \
    }
#define RD_B(DST, CUR, NH)                                                              \
    _Pragma("unroll") for (int ni = 0; ni < 2; ++ni) {                                  \
        const __hip_bfloat16* bp =                                                      \
            sB + (CUR) * 16384 + (wn * 64 + (NH) * 32 + ni * 16 + lr) * 64;             \
        DST[ni][0] = *(const bf16x8_t*)(bp + koff0);                                    \
        DST[ni][1] = *(const bf16x8_t*)(bp + koff1);                                    \
    }
#define MFMA_Q(MH, NH, BF)                                                              \
    _Pragma("unroll") for (int mi = 0; mi < 4; ++mi)                                    \
    _Pragma("unroll") for (int ni = 0; ni < 2; ++ni) {                                  \
        acc[MH][mi][NH][ni] = __builtin_amdgcn_mfma_f32_16x16x32_bf16(                  \
            af[mi][0], BF[ni][0], acc[MH][mi][NH][ni], 0, 0, 0);                        \
        acc[MH][mi][NH][ni] = __builtin_amdgcn_mfma_f32_16x16x32_bf16(                  \
            af[mi][1], BF[ni][1], acc[MH][mi][NH][ni], 0, 0, 0);                        \
    }

    // prologue: stage tile 0 into buf 0 (oldest-first order matches steady state)
    {
        const int k0 = kbase;
        const int ao = aoffk(k0);
        stB(0, 0, k0); stB(1, 0, k0); stB(2, 0, k0); stB(3, 0, k0);
        stA(0, 0, ao); stA(2, 0, ao); stA(1, 0, ao); stA(3, 0, ao);
    }
    VMCNT_BAR(2);                       // B0-3, A0, A2 landed + published

    for (int kt = 0; kt < 26; ++kt) {
        const int cur = kt & 1, nxt = cur ^ 1;
        const int k0n = kbase + (kt + 1) * 64;
        const int aon = aoffk(k0n);
        // ---- P0: MH0 x {NT0,NT1}; stage B0-3 of t+1; NO drain before MFMA
        RD_A(cur, 0);
        RD_B(bf0, cur, 0);
        RD_B(bf1, cur, 1);
        stB(0, nxt, k0n); stB(1, nxt, k0n); stB(2, nxt, k0n); stB(3, nxt, k0n);
        __builtin_amdgcn_s_setprio(1);
        MFMA_Q(0, 0, bf0);
        MFMA_Q(0, 1, bf1);
        __builtin_amdgcn_s_setprio(0);
        VMCNT_BAR(4);                   // A1,A3 of t landed + published
        // ---- P1: MH1 x {NT1,NT0}; stage A0,A2,A1,A3 of t+1
        RD_A(cur, 1);
        stA(0, nxt, aon); stA(2, nxt, aon); stA(1, nxt, aon); stA(3, nxt, aon);
        __builtin_amdgcn_s_setprio(1);
        MFMA_Q(1, 1, bf1);
        MFMA_Q(1, 0, bf0);
        __builtin_amdgcn_s_setprio(0);
        VMCNT_BAR(2);                   // B0-3,A0,A2 of t+1 landed + published
    }

    // epilogue tile 26 (cur = 0, no staging); entry in-flight = 2 [A1,A3]
    RD_A(0, 0);
    RD_B(bf0, 0, 0);
    RD_B(bf1, 0, 1);
    __builtin_amdgcn_s_setprio(1);
    MFMA_Q(0, 0, bf0);
    MFMA_Q(0, 1, bf1);
    __builtin_amdgcn_s_setprio(0);
    VMCNT_BAR(0);                       // A1,A3 of tile 26
    RD_A(0, 1);
    __builtin_amdgcn_s_setprio(1);
    MFMA_Q(1, 1, bf1);
    MFMA_Q(1, 0, bf0);
    __builtin_amdgcn_s_setprio(0);

#undef RD_A
#undef RD_B
#undef MFMA_Q

    // C-write: frag layout col=lane&15, row=(lane>>4)*4+rr
#pragma unroll
    for (int mh = 0; mh < 2; ++mh)
#pragma unroll
        for (int mi = 0; mi < 4; ++mi)
#pragma unroll
            for (int nh = 0; nh < 2; ++nh)
#pragma unroll
                for (int ni = 0; ni < 2; ++ni) {
                    const int col = wn * 64 + nh * 32 + ni * 16 + lr;
#pragma unroll
                    for (int rr = 0; rr < 4; ++rr) {
                        const int row = mblk * 256 + wm * 128 + mh * 64 + mi * 16 + lq * 4 + rr;
                        p[(long)row * 256 + col] = __float2half(acc[mh][mi][nh][ni][rr]);
                    }
                }
}

// ---------------------------------------------------------------- squash (sums 12 fp16 K-splits)
__global__ __launch_bounds__(256) void k_squash(
    const __half* __restrict__ Ph, const float* __restrict__ bias, float* __restrict__ u)
{
    const int g = blockIdx.x * 256 + threadIdx.x;   // < 516096
    const long base = (long)g * 8;
    const int cb = (g & 31) * 8;
    float v[8];
#pragma unroll
    for (int t = 0; t < 8; ++t) v[t] = bias[cb + t];
#pragma unroll
    for (int z = 0; z < 12; ++z) {
        const uint4 r = *(const uint4*)(Ph + z * PSTRIDE_H + base);
        const unsigned wd[4] = {r.x, r.y, r.z, r.w};
#pragma unroll
        for (int h2 = 0; h2 < 4; ++h2) {
            const __half2 hh = *(const __half2*)&wd[h2];
            v[h2 * 2 + 0] += __low2float(hh);
            v[h2 * 2 + 1] += __high2float(hh);
        }
    }
    float sq = 0.f;
#pragma unroll
    for (int t = 0; t < 8; ++t) sq += v[t] * v[t];
    const float sc = sq / ((1.f + sq) * sqrtf(sq + 1e-7f));
#pragma unroll
    for (int t = 0; t < 8; ++t) u[base + t] = v[t] * sc;
}

// ---------------------------------------------------------------- u_hat precompute + fused iter-0 s
// (reverted to the R1/R3-measured grid(2,504) version — the 504-block W-reuse
//  variant cost ~+12 us: halved parallelism on a latency-bound kernel)
__global__ __launch_bounds__(256) void k_uhat2(
    const float* __restrict__ u, const float* __restrict__ W, __half* __restrict__ uh,
    float* __restrict__ sp0)
{
    __shared__ __half lbuf[8 * 64 * 32];   // 32 KB
    __shared__ float red[4 * 256];         // 4 KB
    const int bh   = blockIdx.x;           // 0..1  (b-half)
    const int ic   = blockIdx.y;           // 0..503
    const int tid  = threadIdx.x;
    const int lane = tid & 63;
    const int wv   = tid >> 6;
    const int q    = tid & 3;              // d-quarter
    const int il   = tid >> 2;             // 0..64
    const int i    = ic * 64 + il;

    for (int jg = 0; jg < 5; ++jg) {
        const float* wb0 = W + ((long)(2 * jg) * 32256 + i) * 128 + q * 32;
        const float* wb1 = wb0 + (long)32256 * 128;
        float4 w0[8], w1[8];
#pragma unroll
        for (int t = 0; t < 8; ++t) w0[t] = *(const float4*)(wb0 + t * 4);
#pragma unroll
        for (int t = 0; t < 8; ++t) w1[t] = *(const float4*)(wb1 + t * 4);
        if (jg) __syncthreads();           // previous flush/reduce must finish
#pragma unroll
        for (int b = 0; b < 8; ++b) {
            const float* up = u + ((bh * 8 + b) * 32256 + i) * 8;
            const float4 u0 = *(const float4*)up;
            const float4 u1 = *(const float4*)(up + 4);
            union { __half h[8]; uint4 v; } pk;
#pragma unroll
            for (int d = 0; d < 4; ++d) {
                const float4 a = w0[2 * d], cc = w0[2 * d + 1];
                pk.h[d] = __float2half(
                    a.x * u0.x + a.y * u0.y + a.z * u0.z + a.w * u0.w +
                    cc.x * u1.x + cc.y * u1.y + cc.z * u1.z + cc.w * u1.w);
            }
#pragma unroll
            for (int d = 0; d < 4; ++d) {
                const float4 a = w1[2 * d], cc = w1[2 * d + 1];
                pk.h[4 + d] = __float2half(
                    a.x * u0.x + a.y * u0.y + a.z * u0.z + a.w * u0.w +
                    cc.x * u1.x + cc.y * u1.y + cc.z * u1.z + cc.w * u1.w);
            }
            *(uint4*)&lbuf[(b * 64 + il) * 32 + q * 8] = pk.v;
            float rv[8];
#pragma unroll
            for (int t = 0; t < 8; ++t) rv[t] = __half2float(pk.h[t]);
#pragma unroll
            for (int t = 0; t < 8; ++t) {
                rv[t] += __shfl_xor(rv[t], 4);
                rv[t] += __shfl_xor(rv[t], 8);
                rv[t] += __shfl_xor(rv[t], 16);
                rv[t] += __shfl_xor(rv[t], 32);
            }
            if (lane < 4) {
#pragma unroll
                for (int t = 0; t < 8; ++t)
                    red[wv * 256 + b * 32 + (t >> 2) * 16 + q * 4 + (t & 3)] = rv[t];
            }
        }
        __syncthreads();
        __half* pb = uh + (long)jg * PLANE_H + ((long)(bh * 8) * 32256 + ic * 64) * 32;
#pragma unroll
        for (int b = 0; b < 8; ++b) {
            const uint4 v = *(const uint4*)&lbuf[b * 2048 + tid * 8];
            *(uint4*)(pb + (long)b * (32256 * 32) + tid * 8) = v;
        }
        {
            const float v = red[tid] + red[256 + tid] + red[512 + tid] + red[768 + tid];
            const int bb = tid >> 5, j2 = (tid >> 4) & 1, dd = tid & 15;
            atomicAdd(&sp0[((bh * 8 + bb) * 10 + (2 * jg + j2)) * 16 + dd], 0.1f * v);
        }
    }
}

// ---------------------------------------------------------------- routing iteration
// (reverted to R3 version — no prefetch)
__global__ __launch_bounds__(256) void k_route4(
    const __half* __restrict__ uh, const float* __restrict__ vsum,
    float* __restrict__ sp)
{
    __shared__ float red[4 * 160];
    const int b     = blockIdx.x;      // 16
    const int chunk = blockIdx.y;      // 56
    const int tid   = threadIdx.x;
    const int lane  = tid & 63;
    const int wv    = tid >> 6;
    const int q     = lane & 3;
    const int ig    = lane >> 2;

    float vs[10][4];
#pragma unroll
    for (int j = 0; j < 10; ++j) {
        const float4 t = *(const float4*)(vsum + (b * 10 + j) * 16 + q * 4);
        vs[j][0] = t.x; vs[j][1] = t.y; vs[j][2] = t.z; vs[j][3] = t.w;
    }
    float acc[10][4];
#pragma unroll
    for (int j = 0; j < 10; ++j)
#pragma unroll
        for (int t = 0; t < 4; ++t) acc[j][t] = 0.f;

    const int ib = chunk * 576 + wv * 16 + ig;
    for (int ps = 0; ps < 9; ++ps) {
        const int i = ib + ps * 64;
        const long rb = ((long)b * 32256 + i) * 32 + q * 8;
        uint4 r[5];
#pragma unroll
        for (int jg = 0; jg < 5; ++jg)
            r[jg] = *(const uint4*)(uh + jg * PLANE_H + rb);
        float uhf[10][4];
#pragma unroll
        for (int jg = 0; jg < 5; ++jg) {
            const unsigned wd[4] = {r[jg].x, r[jg].y, r[jg].z, r[jg].w};
#pragma unroll
            for (int h2 = 0; h2 < 4; ++h2) {
                const __half2 hh = *(const __half2*)&wd[h2];
                const int j  = jg * 2 + (h2 >> 1);
                const int d0 = (h2 & 1) * 2;
                uhf[j][d0 + 0] = __low2float(hh);
                uhf[j][d0 + 1] = __high2float(hh);
            }
        }
        float logit[10];
#pragma unroll
        for (int j = 0; j < 10; ++j) {
            float lg = vs[j][0] * uhf[j][0] + vs[j][1] * uhf[j][1]
                     + vs[j][2] * uhf[j][2] + vs[j][3] * uhf[j][3];
            lg += __shfl_xor(lg, 1);
            lg += __shfl_xor(lg, 2);
            logit[j] = lg;
        }
        float mx = logit[0];
#pragma unroll
        for (int j = 1; j < 10; ++j) mx = fmaxf(mx, logit[j]);
        float den = 0.f, e[10];
#pragma unroll
        for (int j = 0; j < 10; ++j) { e[j] = __expf(logit[j] - mx); den += e[j]; }
        const float inv = __builtin_amdgcn_rcpf(den);
#pragma unroll
        for (int j = 0; j < 10; ++j) {
            const float c = e[j] * inv;
#pragma unroll
            for (int t = 0; t < 4; ++t) acc[j][t] = fmaf(c, uhf[j][t], acc[j][t]);
        }
    }
#pragma unroll
    for (int j = 0; j < 10; ++j)
#pragma unroll
        for (int t = 0; t < 4; ++t) {
            float v2 = acc[j][t];
            v2 += __shfl_xor(v2, 4);
            v2 += __shfl_xor(v2, 8);
            v2 += __shfl_xor(v2, 16);
            v2 += __shfl_xor(v2, 32);
            if (lane < 4) red[wv * 160 + j * 16 + q * 4 + t] = v2;
        }
    __syncthreads();
    if (tid < 160) {
        const float s = red[tid] + red[160 + tid] + red[320 + tid] + red[480 + tid];
        atomicAdd(&sp[b * 160 + tid], s);
    }
}

// ---------------------------------------------------------------- v = squash(s); vsum += v
__global__ void k_finish(const float* __restrict__ sp, float* __restrict__ vsum,
                         float* __restrict__ out, const int fin)
{
    const int t = threadIdx.x;
    if (t >= 160) return;          // t = b*10 + j
    const float* s = sp + t * 16;
    float sv[16]; float sq = 0.f;
#pragma unroll
    for (int d = 0; d < 16; ++d) { sv[d] = s[d]; sq += sv[d] * sv[d]; }
    const float sc = sq / ((1.f + sq) * sqrtf(sq + 1e-7f));
    if (fin) {
#pragma unroll
        for (int d = 0; d < 16; ++d) out[t * 16 + d] = sv[d] * sc;
    } else {
        float* vp = vsum + t * 16;
#pragma unroll
        for (int d = 0; d < 16; ++d) vp[d] += sv[d] * sc;
    }
}

extern "C" void kernel_launch(void* const* d_in, const int* in_sizes, int n_in,
                              void* d_out, int out_size, void* d_ws, size_t ws_size,
                              hipStream_t stream)
{
    const float* x   = (const float*)d_in[0];
    const float* c1w = (const float*)d_in[1];
    const float* c1b = (const float*)d_in[2];
    const float* pcw = (const float*)d_in[3];
    const float* pcb = (const float*)d_in[4];
    const float* cW  = (const float*)d_in[5];
    float* out = (float*)d_out;

    char* ws = (char*)d_ws;
    float* u  = (float*)(ws);                                   // 16,515,072 B
    __half* Ph = (__half*)(ws + 16515072);                      // 99,090,432 B
    __hip_bfloat16* y  = (__hip_bfloat16*)(ws + 115605504);     // 42,205,184 B
    __hip_bfloat16* wt = (__hip_bfloat16*)(ws + 157810688);     // 10,616,832 B
    __half* uh = (__half*)(ws + 16515072);                      // 165,150,720 B
    float* sp   = (float*)(ws + 181665792);                     // 3*2560*4 B
    float* vsum = (float*)(ws + 181696512);                     // 2560*4 B

    static int pc8_ok = -1;
    if (pc8_ok < 0)
        pc8_ok = (hipFuncSetAttribute((const void*)k_pcconv8,
                    hipFuncAttributeMaxDynamicSharedMemorySize, 131072) == hipSuccess)
                 ? 1 : 0;

    hipMemsetAsync(sp, 0, (3 * 2560 + 2560) * 4, stream);

    k_conv1<<<16 * 92, 256, 0, stream>>>(x, c1w, c1b, y);
    k_wt<<<20736, 256, 0, stream>>>(pcw, wt);
    if (pc8_ok)
        k_pcconv8<<<dim3(63, 12), 512, 131072, stream>>>(y, wt, Ph);
    else
        k_pcconv3<<<dim3(256, 12), 256, 0, stream>>>(y, wt, Ph);
    k_squash<<<2016, 256, 0, stream>>>(Ph, pcb, u);
    k_uhat2<<<dim3(2, 504), 256, 0, stream>>>(u, cW, uh, sp);     // fused iter-0 s
    k_finish<<<1, 256, 0, stream>>>(sp, vsum, out, 0);            // v0 -> vsum
    k_route4<<<dim3(16, 56), 256, 0, stream>>>(uh, vsum, sp + 2560);
    k_finish<<<1, 256, 0, stream>>>(sp + 2560, vsum, out, 0);     // v1 -> vsum
    k_route4<<<dim3(16, 56), 256, 0, stream>>>(uh, vsum, sp + 5120);
    k_finish<<<1, 256, 0, stream>>>(sp + 5120, vsum, out, 1);     // v2 -> out
}